// Round 9
// baseline (73.417 us; speedup 1.0000x reference)
//
#include <hip/hip_runtime.h>
#include <hip/hip_cooperative_groups.h>

namespace cg = cooperative_groups;

// ---- problem constants (match reference) ----
constexpr int B = 4, N = 4096;       // H*W = 64*64
constexpr int CCH = 13;              // 5 + NC
constexpr float LINE_W = 30.0f;
constexpr double EPS = 1e-05;
constexpr double DICE_W = 5.0;

constexpr int PUSH_SL = 32;                    // pushall slices per eb
constexpr int PUSHB = 8 * PUSH_SL;             // 256 pushall blocks
constexpr int BUCKB = 64;                      // one per (eb, class)
constexpr int ELEMB = 64;                      // 16384 px / 256
constexpr int NB = PUSHB + BUCKB + ELEMB;      // 384 blocks

// ---- ws layout (float-indexed) ----
constexpr int EWP_OFF  = 0;        // [11][256] elemwise per-wave partials
constexpr int PA_OFF   = 2816;     // [256] pushall per-block partials (eb*32+js)
constexpr int BP_OFF   = 3072;     // [64][2] bucket partials (pull, pushsame)
constexpr int CURS_OFF = 3200;     // [64] int class histograms

__device__ inline float logsig(float x) {
    return fminf(x, 0.f) - log1pf(expf(-fabsf(x)));
}
__device__ inline float wave_reduce(float v) {
    #pragma unroll
    for (int off = 32; off > 0; off >>= 1) v += __shfl_down(v, off, 64);
    return v;
}
__device__ inline double wave_reduce_d(double v) {
    #pragma unroll
    for (int off = 32; off > 0; off >>= 1) v += __shfl_down(v, off, 64);
    return v;
}
__device__ inline float rdlane(float v, int k) {
    return __uint_as_float(__builtin_amdgcn_readlane(__float_as_uint(v), k));
}

// ---------------- single cooperative kernel ----------------
// bx [0,256):   pushall. eb=bx>>5, js=bx&31. Compact valid vals of eb into LDS,
//               then 1/32 of the all-pairs push hinge.
// bx [256,320): bucket. bk=bx-256 -> (eb=bk>>3, c=bk&7). Compact class-c vals,
//               full pull + pushsame over the class pairs; publish histogram.
// bx [320,384): elementwise, 256 px/block.
// grid.sync(); block 0 finalizes into out[0].
__global__ __launch_bounds__(256) void coop_kernel(
        const float* __restrict__ outs, const float* __restrict__ gconf,
        const float* __restrict__ gox,  const float* __restrict__ goy,
        const int*   __restrict__ lidx, const int*   __restrict__ ign,
        const int*   __restrict__ fg,   const int*   __restrict__ lid,
        const float* __restrict__ gcls, float* __restrict__ ws,
        float* __restrict__ out) {
    const int bx = blockIdx.x, tid = threadIdx.x;
    const int ln = tid & 63, wv = tid >> 6;

    __shared__ float sv[4096];
    __shared__ unsigned long long smask[16][4];
    __shared__ int scnt[64];
    __shared__ int sbase[64];
    __shared__ int stot;
    __shared__ float red[4][2];

    if (bx < PUSHB + BUCKB) {
        const bool isPush = bx < PUSHB;
        const int eb  = isPush ? (bx >> 5) : ((bx - PUSHB) >> 3);
        const int cls = isPush ? -1 : ((bx - PUSHB) & 7);
        const int js  = isPush ? (bx & 31) : 0;
        const int e = eb >> 2, b = eb & 3;
        const float* pch = outs + ((size_t)b * CCH + 3 + e) * N;
        const int* fgp = fg + b * N;
        const int* gp  = (e ? lid : lidx) + b * N;

        // ---- phase 1: predicate ballots + per-(chunk,wave) counts ----
        unsigned pred = 0;
        float vals[16];
        #pragma unroll
        for (int ch = 0; ch < 16; ++ch) {
            const int n = ch * 256 + tid;
            bool v = fgp[n] > 0;
            if (!isPush) v = v && ((gp[n] & 7) == cls);
            vals[ch] = pch[n];
            const unsigned long long mk = __ballot(v);
            pred |= (v ? 1u : 0u) << ch;
            if (ln == 0) { smask[ch][wv] = mk; scnt[ch * 4 + wv] = __popcll(mk); }
        }
        __syncthreads();

        // ---- exclusive scan over 64 segment counts (one wave) ----
        if (tid < 64) {
            const int c = scnt[tid];
            int inc = c;
            #pragma unroll
            for (int off = 1; off < 64; off <<= 1) {
                const int t = __shfl_up(inc, off, 64);
                if (ln >= off) inc += t;
            }
            sbase[tid] = inc - c;
            if (tid == 63) stot = inc;
        }
        __syncthreads();
        const int m = min(stot, 4096);

        // ---- phase 2: scatter by rank + NaN-pad to 256 multiple ----
        #pragma unroll
        for (int ch = 0; ch < 16; ++ch) {
            if ((pred >> ch) & 1u) {
                const unsigned long long mk = smask[ch][wv];
                const int slot = sbase[ch * 4 + wv] + __popcll(mk & ((1ull << ln) - 1ull));
                if (slot < 4096) sv[slot] = vals[ch];
            }
        }
        const int mpad = (m + 255) & ~255;
        for (int i = m + tid; i < mpad; i += 256) sv[i] = __int_as_float(0x7FC00000);
        __syncthreads();

        // ---- pair sums over LDS ----
        float a0 = 0.f, a1 = 0.f, a2 = 0.f, a3 = 0.f;
        const int nch = (m + 63) >> 6;
        if (isPush) {
            for (int i0 = 0; i0 < m; i0 += 256) {
                const float pi = sv[i0 + tid];
                for (int cj = js; cj < nch; cj += PUSH_SL) {
                    const float jv = sv[cj * 64 + ln];
                    #pragma unroll
                    for (int k = 0; k < 64; k += 2) {
                        const float s0 = rdlane(jv, k);
                        const float s1 = rdlane(jv, k + 1);
                        a0 += fmaxf(1.f - fabsf(pi - s0), 0.f);
                        a2 += fmaxf(1.f - fabsf(pi - s1), 0.f);
                    }
                }
            }
        } else {
            for (int i0 = 0; i0 < m; i0 += 256) {
                const float pi = sv[i0 + tid];
                for (int cj = 0; cj < nch; ++cj) {
                    const float jv = sv[cj * 64 + ln];
                    #pragma unroll
                    for (int k = 0; k < 64; k += 2) {
                        const float d0 = fabsf(pi - rdlane(jv, k));
                        const float d1 = fabsf(pi - rdlane(jv, k + 1));
                        a0 += fmaxf(d0 - 0.5f, 0.f);   // pull
                        a2 += fmaxf(d1 - 0.5f, 0.f);
                        a1 += fmaxf(1.f - d0, 0.f);    // pushsame
                        a3 += fmaxf(1.f - d1, 0.f);
                    }
                }
            }
        }

        // ---- block reduce + publish ----
        const float r0 = wave_reduce(a0 + a2);
        const float r1 = wave_reduce(a1 + a3);
        if (ln == 0) { red[wv][0] = r0; red[wv][1] = r1; }
        __syncthreads();
        if (tid == 0) {
            const float s0 = red[0][0] + red[1][0] + red[2][0] + red[3][0];
            const float s1 = red[0][1] + red[1][1] + red[2][1] + red[3][1];
            if (isPush) {
                ws[PA_OFF + bx] = s0;
            } else {
                const int bk = bx - PUSHB;
                ws[BP_OFF + bk * 2 + 0] = s0;
                ws[BP_OFF + bk * 2 + 1] = s1;
                ((int*)(ws + CURS_OFF))[bk] = m;
            }
        }
    } else {
        // ---- elementwise: 256 px per block ----
        const int blk = bx - (PUSHB + BUCKB);
        const int idx = blk * 256 + tid;           // [0, 16384)
        const int b = idx >> 12, n = idx & 4095;
        const int pix = idx;
        const int pslot = idx >> 6;                // [0,256)
        const float* ob = outs + (size_t)b * CCH * N;

        const float x  = ob[n];
        const float g  = gconf[pix];
        const float im = ign[pix] > 0 ? 1.f : 0.f;
        const float ff = fg[pix] > 0 ? 1.f : 0.f;

        const float ls  = logsig(x);
        const float lns = logsig(-x);
        const float bce = -(g * ls + (1.f - g) * lns);
        const float p   = expf(-bce);
        const float conf = -(LINE_W * g * ls + (1.f - g) * lns);
        const float om  = 1.f - p;
        const float focal = om * om * conf * im;

        const float ps = 1.f / (1.f + expf(-x));
        const float q = 1.f - ps, hh = 1.f - g;
        const float spg = ps * g * im,  spp = ps * ps * im,  sgg = g * g * im;
        const float s2pg = q * hh * im, s2pp = q * q * im,   s2gg = hh * hh * im;

        const float sox = 1.f / (1.f + expf(-ob[1 * N + n]));
        const float soy = 1.f / (1.f + expf(-ob[2 * N + n]));
        const float dx = sox - gox[pix], dy = soy - goy[pix];
        const float se = (dx * dx + dy * dy) * ff;

        float cl = 0.f;
        #pragma unroll
        for (int c = 0; c < 8; ++c) {
            const float z  = ob[(5 + c) * N + n];
            const float gc = gcls[((size_t)b * 8 + c) * N + n];
            cl += -(gc * logsig(z) + (1.f - gc) * logsig(-z));
        }
        cl *= ff;

        float vals[11] = {spg, spp, sgg, s2pg, s2pp, s2gg, im, focal, se, ff, cl};
        #pragma unroll
        for (int qq = 0; qq < 11; ++qq) {
            const float r = wave_reduce(vals[qq]);
            if (ln == 0) ws[EWP_OFF + qq * 256 + pslot] = r;
        }
    }

    // ---------------- grid-wide sync, then block 0 finalizes ----------------
    cg::this_grid().sync();
    if (bx != 0) return;

    __shared__ double ewb[4][7];
    __shared__ double gsum[4];
    __shared__ double pa[8];
    __shared__ double bp[8][2];
    __shared__ double sred[4];

    #pragma unroll
    for (int q = 0; q < 7; ++q) {
        double v = (double)ws[EWP_OFF + q * 256 + tid];
        v = wave_reduce_d(v);
        if (ln == 0) ewb[wv][q] = v;
    }
    for (int q = 7; q < 11; ++q) {
        double v = (double)ws[EWP_OFF + q * 256 + tid];
        v = wave_reduce_d(v);
        if (ln == 0) sred[wv] = v;
        __syncthreads();
        if (tid == 0) gsum[q - 7] = sred[0] + sred[1] + sred[2] + sred[3];
        __syncthreads();
    }
    // pushall partials: PA[256], slot = eb*32 + js -> reduce per 32
    {
        double v = (double)ws[PA_OFF + tid];
        #pragma unroll
        for (int off = 16; off > 0; off >>= 1) v += __shfl_down(v, off, 32);
        if ((tid & 31) == 0) pa[tid >> 5] = v;
    }
    // bucket partials: BP[64][2] -> reduce per 8 (per eb)
    if (tid < 64) {
        double v0 = (double)ws[BP_OFF + tid * 2 + 0];
        double v1 = (double)ws[BP_OFF + tid * 2 + 1];
        #pragma unroll
        for (int off = 4; off > 0; off >>= 1) {
            v0 += __shfl_down(v0, off, 8);
            v1 += __shfl_down(v1, off, 8);
        }
        if ((tid & 7) == 0) { bp[tid >> 3][0] = v0; bp[tid >> 3][1] = v1; }
    }
    __syncthreads();
    if (tid != 0) return;

    const int* curs = (const int*)(ws + CURS_OFF);

    double ign_sum = 0.0, dice = 0.0;
    for (int b = 0; b < B; ++b) {
        const double msum = ewb[b][6];
        ign_sum += msum;
        const double t = 1.0 - (ewb[b][0] + EPS) / (ewb[b][1] + ewb[b][2] + EPS)
                             - (ewb[b][3] + EPS) / (ewb[b][4] + ewb[b][5] + EPS);
        dice += (msum > 0.0) ? t : 0.0;
    }
    const double focal = gsum[0], se = gsum[1], ffs = gsum[2], clsum = gsum[3];
    const double conf_loss = focal / fmax(ign_sum, 1.0) + DICE_W * dice / B;
    const double off_loss  = se / fmax(2.0 * ffs, 1.0);

    double embv[2] = {0.0, 0.0};
    for (int e = 0; e < 2; ++e)
        for (int b = 0; b < B; ++b) {
            const int eb = e * 4 + b;
            double cs = 0.0, nv = 0.0;
            for (int c = 0; c < 8; ++c) {
                const double x = (double)curs[eb * 8 + c];
                cs += x * x; nv += x;
            }
            const double cd = nv * nv - cs;
            const double pull = bp[eb][0] / fmax(cs, 1.0);
            const double pushsum = pa[eb] - bp[eb][1];
            const double push = (cd > 0.0) ? pushsum / fmax(cd, 1.0) : 0.0;
            embv[e] += pull + push;
        }

    const double cls_loss = clsum / fmax(8.0 * ffs, 1.0);
    const double total = conf_loss + 0.5 * off_loss
                       + embv[0] / B + embv[1] / B + cls_loss;
    out[0] = (float)total;
}

extern "C" void kernel_launch(void* const* d_in, const int* in_sizes, int n_in,
                              void* d_out, int out_size, void* d_ws, size_t ws_size,
                              hipStream_t stream) {
    const float* outs  = (const float*)d_in[0];
    const float* gconf = (const float*)d_in[1];
    const float* gox   = (const float*)d_in[2];
    const float* goy   = (const float*)d_in[3];
    const int*   lidx  = (const int*)d_in[4];
    const int*   ign   = (const int*)d_in[5];
    const int*   fg    = (const int*)d_in[6];
    const int*   lid   = (const int*)d_in[7];
    const float* gcls  = (const float*)d_in[8];
    float* ws   = (float*)d_ws;
    float* outp = (float*)d_out;

    void* args[] = {
        (void*)&outs, (void*)&gconf, (void*)&gox, (void*)&goy,
        (void*)&lidx, (void*)&ign,   (void*)&fg,  (void*)&lid,
        (void*)&gcls, (void*)&ws,    (void*)&outp
    };
    hipLaunchCooperativeKernel((const void*)coop_kernel,
                               dim3(NB), dim3(256), args, 0, stream);
}

// Round 10
// 33.571 us; speedup vs baseline: 2.1869x; 2.1869x over previous
//
#include <hip/hip_runtime.h>

// ---- problem constants (match reference) ----
constexpr int B = 4, N = 4096;       // H*W = 64*64
constexpr int CCH = 13;              // 5 + NC
constexpr float LINE_W = 30.0f;
constexpr double EPS = 1e-05;
constexpr double DICE_W = 5.0;

constexpr int PUSH_SL = 32;                    // pushall slices per eb
constexpr int PUSHB = 8 * PUSH_SL;             // 256 pushall blocks
constexpr int BUCKB = 64;                      // one per (eb, class)
constexpr int ELEMB = 64;                      // 16384 px / 256
constexpr int NB = PUSHB + BUCKB + ELEMB;      // 384 blocks

// ---- ws layout (float-indexed) ----
constexpr int EWP_OFF  = 0;        // [11][256] elemwise per-wave partials
constexpr int PA_OFF   = 2816;     // [256] pushall per-block partials (eb*32+js)
constexpr int BP_OFF   = 3072;     // [64][2] bucket partials (pull, pushsame)
constexpr int CURS_OFF = 3200;     // [64] int class histograms

__device__ inline float logsig(float x) {
    return fminf(x, 0.f) - log1pf(expf(-fabsf(x)));
}
__device__ inline float wave_reduce(float v) {
    #pragma unroll
    for (int off = 32; off > 0; off >>= 1) v += __shfl_down(v, off, 64);
    return v;
}
__device__ inline double wave_reduce_d(double v) {
    #pragma unroll
    for (int off = 32; off > 0; off >>= 1) v += __shfl_down(v, off, 64);
    return v;
}
__device__ inline float rdlane(float v, int k) {
    return __uint_as_float(__builtin_amdgcn_readlane(__float_as_uint(v), k));
}

// ---------------- Kernel 1: self-compacting pair blocks + elemwise blocks ----
// bx [0,256):   pushall. eb=bx>>5, js=bx&31. Compact valid vals of eb into LDS,
//               then 1/32 of the all-pairs push hinge.
// bx [256,320): bucket. bk=bx-256 -> (eb=bk>>3, c=bk&7). Compact class-c vals,
//               full pull + pushsame over the class pairs; publish histogram.
// bx [320,384): elementwise, 256 px/block.
__global__ __launch_bounds__(256) void fused_kernel(
        const float* __restrict__ outs, const float* __restrict__ gconf,
        const float* __restrict__ gox,  const float* __restrict__ goy,
        const int*   __restrict__ lidx, const int*   __restrict__ ign,
        const int*   __restrict__ fg,   const int*   __restrict__ lid,
        const float* __restrict__ gcls, float* __restrict__ ws) {
    const int bx = blockIdx.x, tid = threadIdx.x;
    const int ln = tid & 63, wv = tid >> 6;

    __shared__ float sv[4096];
    __shared__ unsigned long long smask[16][4];
    __shared__ int scnt[64];
    __shared__ int sbase[64];
    __shared__ int stot;
    __shared__ float red[4][2];

    if (bx < PUSHB + BUCKB) {
        const bool isPush = bx < PUSHB;
        const int eb  = isPush ? (bx >> 5) : ((bx - PUSHB) >> 3);
        const int cls = isPush ? -1 : ((bx - PUSHB) & 7);
        const int js  = isPush ? (bx & 31) : 0;
        const int e = eb >> 2, b = eb & 3;
        const float* pch = outs + ((size_t)b * CCH + 3 + e) * N;
        const int* fgp = fg + b * N;
        const int* gp  = (e ? lid : lidx) + b * N;

        // ---- phase 1: predicate ballots + per-(chunk,wave) counts ----
        unsigned pred = 0;
        float vals[16];
        #pragma unroll
        for (int ch = 0; ch < 16; ++ch) {
            const int n = ch * 256 + tid;
            bool v = fgp[n] > 0;
            if (!isPush) v = v && ((gp[n] & 7) == cls);
            vals[ch] = pch[n];
            const unsigned long long mk = __ballot(v);
            pred |= (v ? 1u : 0u) << ch;
            if (ln == 0) { smask[ch][wv] = mk; scnt[ch * 4 + wv] = __popcll(mk); }
        }
        __syncthreads();

        // ---- exclusive scan over 64 segment counts (one wave) ----
        if (tid < 64) {
            const int c = scnt[tid];
            int inc = c;
            #pragma unroll
            for (int off = 1; off < 64; off <<= 1) {
                const int t = __shfl_up(inc, off, 64);
                if (ln >= off) inc += t;
            }
            sbase[tid] = inc - c;
            if (tid == 63) stot = inc;
        }
        __syncthreads();
        const int m = min(stot, 4096);

        // ---- phase 2: scatter by rank + NaN-pad to 256 multiple ----
        #pragma unroll
        for (int ch = 0; ch < 16; ++ch) {
            if ((pred >> ch) & 1u) {
                const unsigned long long mk = smask[ch][wv];
                const int slot = sbase[ch * 4 + wv] + __popcll(mk & ((1ull << ln) - 1ull));
                if (slot < 4096) sv[slot] = vals[ch];
            }
        }
        const int mpad = (m + 255) & ~255;
        for (int i = m + tid; i < mpad; i += 256) sv[i] = __int_as_float(0x7FC00000);
        __syncthreads();

        // ---- pair sums over LDS ----
        float a0 = 0.f, a1 = 0.f, a2 = 0.f, a3 = 0.f;
        const int nch = (m + 63) >> 6;
        if (isPush) {
            for (int i0 = 0; i0 < m; i0 += 256) {
                const float pi = sv[i0 + tid];
                for (int cj = js; cj < nch; cj += PUSH_SL) {
                    const float jv = sv[cj * 64 + ln];
                    #pragma unroll
                    for (int k = 0; k < 64; k += 2) {
                        const float s0 = rdlane(jv, k);
                        const float s1 = rdlane(jv, k + 1);
                        a0 += fmaxf(1.f - fabsf(pi - s0), 0.f);
                        a2 += fmaxf(1.f - fabsf(pi - s1), 0.f);
                    }
                }
            }
        } else {
            for (int i0 = 0; i0 < m; i0 += 256) {
                const float pi = sv[i0 + tid];
                for (int cj = 0; cj < nch; ++cj) {
                    const float jv = sv[cj * 64 + ln];
                    #pragma unroll
                    for (int k = 0; k < 64; k += 2) {
                        const float d0 = fabsf(pi - rdlane(jv, k));
                        const float d1 = fabsf(pi - rdlane(jv, k + 1));
                        a0 += fmaxf(d0 - 0.5f, 0.f);   // pull
                        a2 += fmaxf(d1 - 0.5f, 0.f);
                        a1 += fmaxf(1.f - d0, 0.f);    // pushsame
                        a3 += fmaxf(1.f - d1, 0.f);
                    }
                }
            }
        }

        // ---- block reduce + publish ----
        const float r0 = wave_reduce(a0 + a2);
        const float r1 = wave_reduce(a1 + a3);
        if (ln == 0) { red[wv][0] = r0; red[wv][1] = r1; }
        __syncthreads();
        if (tid == 0) {
            const float s0 = red[0][0] + red[1][0] + red[2][0] + red[3][0];
            const float s1 = red[0][1] + red[1][1] + red[2][1] + red[3][1];
            if (isPush) {
                ws[PA_OFF + bx] = s0;
            } else {
                const int bk = bx - PUSHB;
                ws[BP_OFF + bk * 2 + 0] = s0;
                ws[BP_OFF + bk * 2 + 1] = s1;
                ((int*)(ws + CURS_OFF))[bk] = m;
            }
        }
    } else {
        // ---- elementwise: 256 px per block ----
        const int blk = bx - (PUSHB + BUCKB);
        const int idx = blk * 256 + tid;           // [0, 16384)
        const int b = idx >> 12, n = idx & 4095;
        const int pix = idx;
        const int pslot = idx >> 6;                // [0,256)
        const float* ob = outs + (size_t)b * CCH * N;

        const float x  = ob[n];
        const float g  = gconf[pix];
        const float im = ign[pix] > 0 ? 1.f : 0.f;
        const float ff = fg[pix] > 0 ? 1.f : 0.f;

        const float ls  = logsig(x);
        const float lns = logsig(-x);
        const float bce = -(g * ls + (1.f - g) * lns);
        const float p   = expf(-bce);
        const float conf = -(LINE_W * g * ls + (1.f - g) * lns);
        const float om  = 1.f - p;
        const float focal = om * om * conf * im;

        const float ps = 1.f / (1.f + expf(-x));
        const float q = 1.f - ps, hh = 1.f - g;
        const float spg = ps * g * im,  spp = ps * ps * im,  sgg = g * g * im;
        const float s2pg = q * hh * im, s2pp = q * q * im,   s2gg = hh * hh * im;

        const float sox = 1.f / (1.f + expf(-ob[1 * N + n]));
        const float soy = 1.f / (1.f + expf(-ob[2 * N + n]));
        const float dx = sox - gox[pix], dy = soy - goy[pix];
        const float se = (dx * dx + dy * dy) * ff;

        float cl = 0.f;
        #pragma unroll
        for (int c = 0; c < 8; ++c) {
            const float z  = ob[(5 + c) * N + n];
            const float gc = gcls[((size_t)b * 8 + c) * N + n];
            cl += -(gc * logsig(z) + (1.f - gc) * logsig(-z));
        }
        cl *= ff;

        float vals[11] = {spg, spp, sgg, s2pg, s2pp, s2gg, im, focal, se, ff, cl};
        #pragma unroll
        for (int qq = 0; qq < 11; ++qq) {
            const float r = wave_reduce(vals[qq]);
            if (ln == 0) ws[EWP_OFF + qq * 256 + pslot] = r;
        }
    }
}

// ---------------- Kernel 2: finalize (1 block, 256 threads) ----------------
__global__ __launch_bounds__(256) void finalize_kernel(
        const float* __restrict__ ws, float* __restrict__ out) {
    const int tid = threadIdx.x, ln = tid & 63, wv = tid >> 6;
    __shared__ double ewb[4][7];
    __shared__ double gsum[4];
    __shared__ double pa[8];
    __shared__ double bp[8][2];
    __shared__ double sred[4];

    #pragma unroll
    for (int q = 0; q < 7; ++q) {
        double v = (double)ws[EWP_OFF + q * 256 + tid];
        v = wave_reduce_d(v);
        if (ln == 0) ewb[wv][q] = v;
    }
    for (int q = 7; q < 11; ++q) {
        double v = (double)ws[EWP_OFF + q * 256 + tid];
        v = wave_reduce_d(v);
        if (ln == 0) sred[wv] = v;
        __syncthreads();
        if (tid == 0) gsum[q - 7] = sred[0] + sred[1] + sred[2] + sred[3];
        __syncthreads();
    }
    // pushall partials: PA[256], slot = eb*32 + js -> reduce per 32
    {
        double v = (double)ws[PA_OFF + tid];
        #pragma unroll
        for (int off = 16; off > 0; off >>= 1) v += __shfl_down(v, off, 32);
        if ((tid & 31) == 0) pa[tid >> 5] = v;
    }
    // bucket partials: BP[64][2] -> reduce per 8 (per eb)
    if (tid < 64) {
        double v0 = (double)ws[BP_OFF + tid * 2 + 0];
        double v1 = (double)ws[BP_OFF + tid * 2 + 1];
        #pragma unroll
        for (int off = 4; off > 0; off >>= 1) {
            v0 += __shfl_down(v0, off, 8);
            v1 += __shfl_down(v1, off, 8);
        }
        if ((tid & 7) == 0) { bp[tid >> 3][0] = v0; bp[tid >> 3][1] = v1; }
    }
    __syncthreads();
    if (tid != 0) return;

    const int* curs = (const int*)(ws + CURS_OFF);

    double ign_sum = 0.0, dice = 0.0;
    for (int b = 0; b < B; ++b) {
        const double msum = ewb[b][6];
        ign_sum += msum;
        const double t = 1.0 - (ewb[b][0] + EPS) / (ewb[b][1] + ewb[b][2] + EPS)
                             - (ewb[b][3] + EPS) / (ewb[b][4] + ewb[b][5] + EPS);
        dice += (msum > 0.0) ? t : 0.0;
    }
    const double focal = gsum[0], se = gsum[1], ffs = gsum[2], clsum = gsum[3];
    const double conf_loss = focal / fmax(ign_sum, 1.0) + DICE_W * dice / B;
    const double off_loss  = se / fmax(2.0 * ffs, 1.0);

    double embv[2] = {0.0, 0.0};
    for (int e = 0; e < 2; ++e)
        for (int b = 0; b < B; ++b) {
            const int eb = e * 4 + b;
            double cs = 0.0, nv = 0.0;
            for (int c = 0; c < 8; ++c) {
                const double x = (double)curs[eb * 8 + c];
                cs += x * x; nv += x;
            }
            const double cd = nv * nv - cs;
            const double pull = bp[eb][0] / fmax(cs, 1.0);
            const double pushsum = pa[eb] - bp[eb][1];
            const double push = (cd > 0.0) ? pushsum / fmax(cd, 1.0) : 0.0;
            embv[e] += pull + push;
        }

    const double cls_loss = clsum / fmax(8.0 * ffs, 1.0);
    const double total = conf_loss + 0.5 * off_loss
                       + embv[0] / B + embv[1] / B + cls_loss;
    out[0] = (float)total;
}

extern "C" void kernel_launch(void* const* d_in, const int* in_sizes, int n_in,
                              void* d_out, int out_size, void* d_ws, size_t ws_size,
                              hipStream_t stream) {
    const float* outs  = (const float*)d_in[0];
    const float* gconf = (const float*)d_in[1];
    const float* gox   = (const float*)d_in[2];
    const float* goy   = (const float*)d_in[3];
    const int*   lidx  = (const int*)d_in[4];
    const int*   ign   = (const int*)d_in[5];
    const int*   fg    = (const int*)d_in[6];
    const int*   lid   = (const int*)d_in[7];
    const float* gcls  = (const float*)d_in[8];
    float* ws = (float*)d_ws;

    fused_kernel<<<NB, 256, 0, stream>>>(outs, gconf, gox, goy, lidx, ign, fg, lid, gcls, ws);
    finalize_kernel<<<1, 256, 0, stream>>>(ws, (float*)d_out);
}